// Round 13
// baseline (391.511 us; speedup 1.0000x reference)
//
#include <hip/hip_runtime.h>
#include <hip/hip_bf16.h>

// B=4, L=4096, D=1024, H=16, M=4, dk=64, n=1024. All-bf16 MFMA pipeline.
// R20: fix R19's element-vs-byte bug. Sub-tile is 4096 ELEMENTS (8KB); R19
// used 8192 (the byte count) as the element offset -> stage wrote past
// Ks[nb]/Vs[nb] (corrupting Vs[0]/Ps for nb=1), absmax 0.68. Fix: 4096 in
// stage dests + compute bases. Everything else identical to R19: attn KVBLK
// 64->128 (two 64-key halves per barrier, barriers 16->8, per-interval
// compute ~= load latency), LDS 80KB, 2 blocks/CU, per-subtile layouts
// byte-identical to R16 (385.4us). gemm_k / cvt / cvt_w_t / vtrans unchanged.

typedef __attribute__((ext_vector_type(8))) short short8;
typedef __attribute__((ext_vector_type(8))) unsigned short ushort8v;
typedef __attribute__((ext_vector_type(4))) float floatx4;

__device__ __forceinline__ float b2f(unsigned short h) {
    union { unsigned int u; float f; } v; v.u = ((unsigned int)h) << 16; return v.f;
}
__device__ __forceinline__ unsigned short f2b(float f) {
    union { float f; unsigned int u; } v; v.f = f;
    unsigned int r = v.u + 0x7fffu + ((v.u >> 16) & 1u);
    return (unsigned short)(r >> 16);
}
__device__ __forceinline__ unsigned int fbits(float f) {
    union { float f; unsigned int u; } v; v.f = f; return v.u;
}
__device__ __forceinline__ void async_copy16(const unsigned short* g, unsigned short* l) {
    __builtin_amdgcn_global_load_lds((const __attribute__((address_space(1))) void*)g,
                                     (__attribute__((address_space(3))) void*)l, 16, 0, 0);
}

// ---------------- fp32 -> bf16 convert (x): grid-stride, 16B stores ----------------
__global__ __launch_bounds__(256)
void cvt_kernel(const float* __restrict__ in, unsigned short* __restrict__ out, int n8) {
    for (int i = blockIdx.x * 256 + threadIdx.x; i < n8; i += 2048 * 256) {
        float4 a = ((const float4*)in)[2 * (size_t)i];
        float4 b = ((const float4*)in)[2 * (size_t)i + 1];
        ushort8v o;
        o[0] = f2b(a.x); o[1] = f2b(a.y); o[2] = f2b(a.z); o[3] = f2b(a.w);
        o[4] = f2b(b.x); o[5] = f2b(b.y); o[6] = f2b(b.z); o[7] = f2b(b.w);
        *(ushort8v*)(out + 8 * (size_t)i) = o;
    }
}

// ---------------- W [K][N] fp32 -> Wt [N][K] bf16, all 4 weights in one grid ----------------
__global__ __launch_bounds__(256)
void cvt_w_t(const float* __restrict__ Wq, const float* __restrict__ Wk,
             const float* __restrict__ Wv, const float* __restrict__ Wo,
             unsigned short* __restrict__ Wt3, unsigned short* __restrict__ Wot, float s0) {
    __shared__ float tile[64][65];
    const int kt = blockIdx.x, nt = blockIdx.y, z = blockIdx.z;
    const float* W = (z == 0) ? Wq : (z == 1) ? Wk : (z == 2) ? Wv : Wo;
    unsigned short* Wt = (z < 3) ? (Wt3 + (size_t)z * 1048576) : Wot;
    const float sc = (z == 0) ? s0 : 1.0f;
    const int t = threadIdx.x;
    const int r = t >> 2, cg = t & 3;
    const float* src = W + (size_t)(kt * 64 + r) * 1024 + nt * 64 + cg * 16;
#pragma unroll
    for (int j = 0; j < 4; j++) {
        float4 v = *(const float4*)(src + j * 4);
        tile[r][cg * 16 + j * 4 + 0] = v.x;
        tile[r][cg * 16 + j * 4 + 1] = v.y;
        tile[r][cg * 16 + j * 4 + 2] = v.z;
        tile[r][cg * 16 + j * 4 + 3] = v.w;
    }
    __syncthreads();
    unsigned short* dst = Wt + (size_t)(nt * 64 + r) * 1024 + kt * 64 + cg * 16;
    ushort8v o0, o1;
#pragma unroll
    for (int j = 0; j < 8; j++) o0[j] = f2b(tile[cg * 16 + j][r] * sc);
#pragma unroll
    for (int j = 0; j < 8; j++) o1[j] = f2b(tile[cg * 16 + 8 + j][r] * sc);
    *(ushort8v*)(dst) = o0;
    *(ushort8v*)(dst + 8) = o1;
}

// ---------------- GEMM: C[M][N] = A[M][K] * Bt[N][K]^T + bias*bs ----------------
// BM=256, BN=128, BK=64; 4 waves (2x2), 8x4 accum/wave = 64 MFMA per K-iter.
// LDS XOR swizzle: chunk(row,kc) @ elem (row*8 + (kc^(row&7)))*8.
// Grid 512*nz: xcd=id&7, q=id>>3, tileM=xcd*8+(q&7), rz=q>>3, tileN=rz&7, z=rz>>3.
template <bool F32OUT>
__global__ __launch_bounds__(256, 2)
void gemm_k(const unsigned short* __restrict__ A,
            const unsigned short* __restrict__ BtBase,
            const float* __restrict__ bias0,
            const float* __restrict__ bias1,
            const float* __restrict__ bias2,
            void* __restrict__ OutBase, float s0) {
    constexpr int K = 1024, N = 1024;
    __shared__ __align__(16) unsigned short As[256 * 64];
    __shared__ __align__(16) unsigned short Bs[128 * 64];
    const int id = blockIdx.x;
    const int xcd = id & 7;
    const int q = id >> 3;
    const int tileM = xcd * 8 + (q & 7);
    const int rz = q >> 3;
    const int tileN = rz & 7;
    const int z = rz >> 3;
    const unsigned short* Bt = BtBase + (size_t)z * (1024 * 1024);
    const float* bias = (z == 0) ? bias0 : (z == 1 ? bias1 : bias2);
    const float bs = (z == 0) ? s0 : 1.0f;
    const int tid = threadIdx.x, w = tid >> 6, lane = tid & 63;
    const int wr = w >> 1, wc = w & 1;
    const int g = lane >> 4, c = lane & 15;
    const int c7 = c & 7;
    const int r8 = lane >> 3, j8 = lane & 7;
    const int kcs = (j8 ^ r8) * 8;   // swizzled k-chunk this lane stages

    floatx4 acc[8][4];
#pragma unroll
    for (int i = 0; i < 8; i++)
#pragma unroll
        for (int jj = 0; jj < 4; jj++) acc[i][jj] = (floatx4){0.f, 0.f, 0.f, 0.f};

    for (int kt = 0; kt < K / 64; ++kt) {
        __syncthreads();
#pragma unroll
        for (int t = 0; t < 8; t++) {          // A: 32 segs of 8 rows
            int seg = w * 8 + t;
            int rowA = tileM * 256 + seg * 8 + r8;
            async_copy16(A + (size_t)rowA * K + kt * 64 + kcs, As + seg * 512);
        }
#pragma unroll
        for (int t = 0; t < 4; t++) {          // B: 16 segs of 8 rows
            int seg = w * 4 + t;
            int rowB = tileN * 128 + seg * 8 + r8;
            async_copy16(Bt + (size_t)rowB * K + kt * 64 + kcs, Bs + seg * 512);
        }
        __syncthreads();
#pragma unroll
        for (int ks = 0; ks < 2; ks++) {
            const int kx = ((ks * 4 + g) ^ c7) * 8;
            short8 bf[4];
#pragma unroll
            for (int ct = 0; ct < 4; ct++)
                bf[ct] = *(const short8*)(Bs + (wc * 64 + ct * 16 + c) * 64 + kx);
#pragma unroll
            for (int rt = 0; rt < 8; rt++) {
                short8 af = *(const short8*)(As + (wr * 128 + rt * 16 + c) * 64 + kx);
#pragma unroll
                for (int ct = 0; ct < 4; ct++)
                    acc[rt][ct] = __builtin_amdgcn_mfma_f32_16x16x32_bf16(af, bf[ct], acc[rt][ct], 0, 0, 0);
            }
        }
    }
#pragma unroll
    for (int ct = 0; ct < 4; ct++) {
        int col = tileN * 128 + wc * 64 + ct * 16 + c;
        float bvv = bias[col] * bs;
#pragma unroll
        for (int rt = 0; rt < 8; rt++) {
            int row0 = tileM * 256 + wr * 128 + rt * 16 + g * 4;
#pragma unroll
            for (int r = 0; r < 4; r++) {
                float v = acc[rt][ct][r] + bvv;
                if (F32OUT) {
                    ((float*)OutBase)[(size_t)(row0 + r) * N + col] = v;
                } else {
                    ((unsigned short*)OutBase)[(size_t)z * (16384ull * 1024ull) +
                                               (size_t)(row0 + r) * N + col] = f2b(v);
                }
            }
        }
    }
}

// ---------------- V transpose: v[B,L,D] -> Vt[slice=(b,h,m)][d=64][i=1024] ----------------
__global__ __launch_bounds__(256)
void vtrans(const unsigned short* __restrict__ V, unsigned short* __restrict__ Vt) {
    __shared__ unsigned short tile[64 * 72];
    const int it = blockIdx.x, s = blockIdx.y;
    const int m = s & 3, h = (s >> 2) & 15, b = s >> 6;
    const int tid = threadIdx.x;
    {
        int il = tid >> 2, cg = tid & 3;
        const unsigned short* gsrc =
            V + ((size_t)b * 4096 + m + 4 * (it * 64 + il)) * 1024 + h * 64 + cg * 16;
        *(ushort8v*)(tile + il * 72 + cg * 16) = *(const ushort8v*)gsrc;
        *(ushort8v*)(tile + il * 72 + cg * 16 + 8) = *(const ushort8v*)(gsrc + 8);
    }
    __syncthreads();
    {
        int dl = tid >> 2, ig = (tid & 3) * 16;
        ushort8v o0, o1;
#pragma unroll
        for (int j = 0; j < 8; j++) o0[j] = tile[(ig + j) * 72 + dl];
#pragma unroll
        for (int j = 0; j < 8; j++) o1[j] = tile[(ig + 8 + j) * 72 + dl];
        unsigned short* dst = Vt + (size_t)s * 65536 + (size_t)dl * 1024 + it * 64 + ig;
        *(ushort8v*)dst = o0;
        *(ushort8v*)(dst + 8) = o1;
    }
}

// ---------------- Attention ----------------
// Grid 1024 blocks x 512 thr (8 waves); decode xcd=id&7, qq=id>>3,
// s=xcd*32+(qq>>2), qt=qq&3. Each block: 256 q-rows of one slice; wave w owns
// rows [w*32, w*32+32). 128-key big-tiles (8 total), each staged as two
// 64-key sub-tiles (4096 elements each) in R16's exact per-subtile layout,
// computed back-to-back between barriers. Double-buffered; one __syncthreads
// per big tile. Per-wave compute identical to R16.
__global__ __launch_bounds__(512, 4)
void attn_k(const unsigned short* __restrict__ Qg,
            const unsigned short* __restrict__ Kg,
            const unsigned short* __restrict__ Vt,
            unsigned short* __restrict__ Og) {
    __shared__ __align__(16) unsigned short Ks[2][128 * 64];  // [buf][half*4096 + seg*512]
    __shared__ __align__(16) unsigned short Vs[2][128 * 64];
    __shared__ __align__(16) unsigned short Ps[8 * 1024];     // per-wave [rt*4+gr][c][8] (one kc half)

    const int id = blockIdx.x;
    const int xcd = id & 7;
    const int qq = id >> 3;
    const int s = xcd * 32 + (qq >> 2);
    const int qt = qq & 3;
    const int m = s & 3, h = (s >> 2) & 15, b = s >> 6;
    const int tid = threadIdx.x, w = tid >> 6, lane = tid & 63;
    const int g = lane >> 4, c = lane & 15;
    const size_t rowBase = (size_t)b * 4096;

    // Q fragments straight to registers (read-once data; 16B/lane)
    short8 qf[2][2];
#pragma unroll
    for (int rt = 0; rt < 2; rt++)
#pragma unroll
        for (int ks = 0; ks < 2; ks++)
            qf[rt][ks] = *(const short8*)(Qg +
                (rowBase + (size_t)(m + 4 * (qt * 256 + w * 32 + rt * 16 + c))) * 1024 +
                h * 64 + ks * 32 + g * 8);

    // staging pointers: wave w stages seg w (token-halves w>>1, dim-half w&1)
    const unsigned short* kPtr =
        Kg + (rowBase + (size_t)(m + 4 * ((w >> 1) * 16 + c))) * 1024 + h * 64 + (w & 1) * 32 + g * 8;
    const unsigned short* vPtr =
        Vt + (size_t)s * 65536 + (size_t)((w >> 1) * 16 + c) * 1024 + (w & 1) * 32 + g * 8;

    // all-ones B-fragment: l-column trick
    short8 ones;
#pragma unroll
    for (int j = 0; j < 8; j++) ones[j] = (short)0x3F80;   // bf16 1.0

    floatx4 oacc[2][4], lacc[2];
#pragma unroll
    for (int rt = 0; rt < 2; rt++) {
        lacc[rt] = (floatx4){0.f, 0.f, 0.f, 0.f};
#pragma unroll
        for (int dt = 0; dt < 4; dt++) oacc[rt][dt] = (floatx4){0.f, 0.f, 0.f, 0.f};
    }

    unsigned short* Pw = Ps + w * 1024;   // per-wave 2KB half-buffer

    // stage one 128-key big tile (two 64-key sub-tiles, 4096 elems each) into buffer nb
    auto stage = [&](int nb) {
        async_copy16(kPtr,          &Ks[nb][w * 512]);
        async_copy16(kPtr + 262144, &Ks[nb][4096 + w * 512]);   // +64 keys (256 token-rows)
        async_copy16(vPtr,          &Vs[nb][w * 512]);
        async_copy16(vPtr + 64,     &Vs[nb][4096 + w * 512]);   // +64 along i-dim
        kPtr += 524288;   // 512 token-rows * 1024 elems (128 keys)
        vPtr += 128;      // 128 keys along i-dim
    };

    // compute one 64-key sub-tile at Ks/Vs base + half*4096 (elements)
    auto compute = [&](int buf, int half) {
        const unsigned short* Kb = &Ks[buf][half * 4096];
        const unsigned short* Vb = &Vs[buf][half * 4096];
        // S^T[key][q] = K·Q^T : A=K (4 key-tiles), B=Q (2 q-tiles, regs)
        floatx4 sacc[4][2];
#pragma unroll
        for (int k4 = 0; k4 < 4; k4++)
#pragma unroll
            for (int rt = 0; rt < 2; rt++) sacc[k4][rt] = (floatx4){0.f, 0.f, 0.f, 0.f};
        __builtin_amdgcn_s_setprio(1);
#pragma unroll
        for (int ks = 0; ks < 2; ks++) {
            short8 kf[4];
#pragma unroll
            for (int k4 = 0; k4 < 4; k4++)
                kf[k4] = *(const short8*)(Kb + (((k4 * 2 + ks) * 4 + g) * 16 + c) * 8);
#pragma unroll
            for (int k4 = 0; k4 < 4; k4++)
#pragma unroll
                for (int rt = 0; rt < 2; rt++)
                    sacc[k4][rt] = __builtin_amdgcn_mfma_f32_16x16x32_bf16(kf[k4], qf[rt][ks], sacc[k4][rt], 0, 0, 0);
        }
        __builtin_amdgcn_s_setprio(0);

        // per kc half: p = exp2(s) -> +0x8000 + v_perm_b32 pack -> Pw -> PV
#pragma unroll
        for (int kc = 0; kc < 2; kc++) {
#pragma unroll
            for (int kh = 0; kh < 2; kh++) {
                const int k4 = kc * 2 + kh;
                const int gr = kh * 2 + (g >> 1);
                const int j0 = (g & 1) * 4;
#pragma unroll
                for (int rt = 0; rt < 2; rt++) {
                    unsigned int u0 = fbits(__builtin_amdgcn_exp2f(sacc[k4][rt][0])) + 0x8000u;
                    unsigned int u1 = fbits(__builtin_amdgcn_exp2f(sacc[k4][rt][1])) + 0x8000u;
                    unsigned int u2 = fbits(__builtin_amdgcn_exp2f(sacc[k4][rt][2])) + 0x8000u;
                    unsigned int u3 = fbits(__builtin_amdgcn_exp2f(sacc[k4][rt][3])) + 0x8000u;
                    uint2 pk;
                    pk.x = __builtin_amdgcn_perm(u1, u0, 0x07060302u);  // [e1.hi16 : e0.hi16]
                    pk.y = __builtin_amdgcn_perm(u3, u2, 0x07060302u);
                    *(uint2*)(Pw + ((rt * 4 + gr) * 16 + c) * 8 + j0) = pk;
                }
            }
            // O += P·V ; l += P·1  (ones B-frag -> l lands oacc-aligned per row)
            short8 pf[2], vf[4];
#pragma unroll
            for (int rt = 0; rt < 2; rt++)
                pf[rt] = *(const short8*)(Pw + ((rt * 4 + g) * 16 + c) * 8);
#pragma unroll
            for (int dt = 0; dt < 4; dt++)
                vf[dt] = *(const short8*)(Vb + (((dt * 2 + kc) * 4 + g) * 16 + c) * 8);
            __builtin_amdgcn_s_setprio(1);
#pragma unroll
            for (int rt = 0; rt < 2; rt++) {
                lacc[rt] = __builtin_amdgcn_mfma_f32_16x16x32_bf16(pf[rt], ones, lacc[rt], 0, 0, 0);
#pragma unroll
                for (int dt = 0; dt < 4; dt++)
                    oacc[rt][dt] = __builtin_amdgcn_mfma_f32_16x16x32_bf16(pf[rt], vf[dt], oacc[rt][dt], 0, 0, 0);
            }
            __builtin_amdgcn_s_setprio(0);
        }
    };

    // prologue: stage big-tile 0 into buf 0
    stage(0);
    __syncthreads();

    // steady: prefetch bt+1 into buf^1, compute both halves of bt, barrier
    for (int bt = 0; bt < 7; ++bt) {
        const int buf = bt & 1;
        stage(buf ^ 1);
        compute(buf, 0);
        compute(buf, 1);
        __syncthreads();
    }
    compute(1, 0);   // bt = 7 (buf 1), no further staging
    compute(1, 1);

    // epilogue: l is already per-row in matching slots; normalize and scatter
#pragma unroll
    for (int rt = 0; rt < 2; rt++) {
#pragma unroll
        for (int r = 0; r < 4; r++) {
            float inv = 1.0f / lacc[rt][r];
            int token = m + 4 * (qt * 256 + w * 32 + rt * 16 + g * 4 + r);
            size_t rowOff = (rowBase + token) * 1024 + h * 64;
#pragma unroll
            for (int dt = 0; dt < 4; dt++)
                Og[rowOff + dt * 16 + c] = f2b(oacc[rt][dt][r] * inv);
        }
    }
}

extern "C" void kernel_launch(void* const* d_in, const int* in_sizes, int n_in,
                              void* d_out, int out_size, void* d_ws, size_t ws_size,
                              hipStream_t stream) {
    const float* x  = (const float*)d_in[0];
    const float* Wq = (const float*)d_in[1];
    const float* bq = (const float*)d_in[2];
    const float* Wk = (const float*)d_in[3];
    const float* bk = (const float*)d_in[4];
    const float* Wv = (const float*)d_in[5];
    const float* bv = (const float*)d_in[6];
    const float* Wo = (const float*)d_in[7];
    const float* bo = (const float*)d_in[8];

    const float SC = 0.18033688011112042f;  // (1/8) * log2(e), folded into Wq/bq

    char* ws = (char*)d_ws;
    const size_t SZ = 33554432;  // 32 MB = 16M bf16
    unsigned short* xb  = (unsigned short*)(ws);          // dead after QKV gemm
    unsigned short* Vtp = (unsigned short*)(ws);          // reuses xb region
    unsigned short* qb  = (unsigned short*)(ws + SZ);     // q,k,v contiguous
    unsigned short* ob  = (unsigned short*)(ws + 4 * SZ);
    unsigned short* Wt3 = (unsigned short*)(ws + 5 * SZ);
    unsigned short* Wot = Wt3 + 3ull * 1024 * 1024;

    cvt_kernel<<<2048, 256, 0, stream>>>(x, xb, 2097152);
    cvt_w_t<<<dim3(16, 16, 4), 256, 0, stream>>>(Wq, Wk, Wv, Wo, Wt3, Wot, SC);
    gemm_k<false><<<1536, 256, 0, stream>>>(xb, Wt3, bq, bk, bv, qb, SC);
    vtrans<<<dim3(16, 256), 256, 0, stream>>>(qb + 2ull * 16777216ull, Vtp);
    attn_k<<<1024, 512, 0, stream>>>(qb, qb + 16777216ull, Vtp, ob);
    gemm_k<true><<<512, 256, 0, stream>>>(ob, Wot, bo, bo, bo, d_out, 1.0f);
}